// Round 8
// baseline (205.381 us; speedup 1.0000x reference)
//
#include <hip/hip_runtime.h>
#include <hip/hip_bf16.h>

// Problem constants (B=4, C=256, H=W=64, N=4096, G=32, DQK=32)
#define NB 4
#define CD 256
#define NT 4096
#define DQ 32

typedef __attribute__((ext_vector_type(8))) __bf16 bf16x8;
typedef __attribute__((ext_vector_type(16))) float float16v;
typedef __attribute__((ext_vector_type(4))) unsigned int uint4v;
typedef __attribute__((ext_vector_type(2))) unsigned int uint2v;

#if __has_builtin(__builtin_amdgcn_exp2f)
#define EXP2(x) __builtin_amdgcn_exp2f(x)
#else
#define EXP2(x) exp2f(x)
#endif

__device__ inline unsigned short f2bf(float f) {
  unsigned u = __float_as_uint(f);
  u += 0x7fffu + ((u >> 16) & 1u);
  return (unsigned short)(u >> 16);
}

// ---------------------------------------------------------------------------
// gn_pack: blocks 0..127 do the full GroupNorm for one (b,g) — stats pass +
// apply pass, block-local (no grid dep) — writing h[B][N][C] bf16. Blocks
// 128..416 pack weights to bf16 (scale2 = log2(e)/sqrt(32) folded into wq/bq
// so attention uses exp2 directly). One dispatch replaces three.
// ---------------------------------------------------------------------------
__global__ __launch_bounds__(512) void gn_pack(
    const float* __restrict__ x, const float* __restrict__ gamma,
    const float* __restrict__ beta, const float* __restrict__ wq,
    const float* __restrict__ wk, const float* __restrict__ wv,
    const float* __restrict__ wp, const float* __restrict__ bq,
    const float* __restrict__ bk, const float* __restrict__ bv,
    unsigned short* __restrict__ h, unsigned short* __restrict__ wqkv,
    unsigned short* __restrict__ wpb, float* __restrict__ bias) {
  int bx = blockIdx.x;
  int tid = threadIdx.x;
  if (bx < 128) {
    int bg = bx;  // b*32+g
    const float4* xp = (const float4*)(x + (size_t)bg * 32768);
    float s = 0.f, ss = 0.f;
#pragma unroll
    for (int i = 0; i < 16; i++) {
      float4 v = xp[tid + 512 * i];
      s += v.x + v.y + v.z + v.w;
      ss += v.x * v.x + v.y * v.y + v.z * v.z + v.w * v.w;
    }
    int wid = tid >> 6, lane = tid & 63;
#pragma unroll
    for (int off = 32; off >= 1; off >>= 1) {
      s += __shfl_xor(s, off);
      ss += __shfl_xor(ss, off);
    }
    __shared__ float red[16];
    __shared__ float stat[2];
    if (lane == 0) { red[wid] = s; red[8 + wid] = ss; }
    __syncthreads();
    if (tid == 0) {
      float S = 0.f, SS = 0.f;
#pragma unroll
      for (int j = 0; j < 8; j++) { S += red[j]; SS += red[8 + j]; }
      float mu = S * (1.f / 32768.f);
      float var = SS * (1.f / 32768.f) - mu * mu;
      stat[0] = mu;
      stat[1] = rsqrtf(var + 1e-5f);
    }
    __syncthreads();
    float mu = stat[0], rstd = stat[1];
    int b = bg >> 5, g = bg & 31, c0 = g * 8;
    float gam[8], bet[8];
#pragma unroll
    for (int j = 0; j < 8; j++) {
      gam[j] = gamma[c0 + j];
      bet[j] = beta[c0 + j];
    }
    const float* xb = x + (size_t)bg * 32768;
#pragma unroll
    for (int i = 0; i < 8; i++) {
      int n = 512 * i + tid;
      unsigned short hv[8];
#pragma unroll
      for (int j = 0; j < 8; j++) {
        float y = (xb[j * NT + n] - mu) * rstd * gam[j] + bet[j];
        hv[j] = f2bf(y);
      }
      *(uint4v*)(h + ((size_t)(b * NT + n) * CD + c0)) = *(uint4v*)hv;
    }
  } else {
    const float scale2 = 0.2550348909867343f;  // log2(e)/sqrt(32)
    int i = (bx - 128) * 512 + tid;
    if (i < 320 * 256) {
      int j = i >> 8, c = i & 255;
      float v;
      if (j < 32) v = wq[j * 256 + c] * scale2;
      else if (j < 64) v = wk[(j - 32) * 256 + c];
      else v = wv[(j - 64) * 256 + c];
      wqkv[i] = f2bf(v);
    } else if (i < 320 * 256 + 256 * 256) {
      int k = i - 320 * 256;
      wpb[k] = f2bf(wp[k]);
    } else if (i < 320 * 256 + 256 * 256 + 320) {
      int j = i - (320 * 256 + 256 * 256);
      float v;
      if (j < 32) v = bq[j] * scale2;
      else if (j < 64) v = bk[j - 32];
      else v = bv[j - 64];
      bias[j] = v;
    }
  }
}

// ---------------------------------------------------------------------------
// QKV GEMM — zero LDS, zero barriers (proven R5 form).
// ---------------------------------------------------------------------------
__global__ __launch_bounds__(256) void qkv_gemm(
    const unsigned short* __restrict__ A, const unsigned short* __restrict__ H,
    const float* __restrict__ bias, unsigned short* __restrict__ qk,
    unsigned short* __restrict__ v) {
  int nt = blockIdx.x, mt = blockIdx.y, b = blockIdx.z;
  int tid = threadIdx.x, lane = tid & 63;
  int w = tid >> 6, mi = w & 1, ni = w >> 1;
  int l31 = lane & 31, hh = lane >> 5;
  int m_base = mt * 64 + 32 * mi;
  int n_base = nt * 128 + 64 * ni;
  const unsigned short* Arow = A + (size_t)(m_base + l31) * 256 + 8 * hh;
  const unsigned short* Hb = H + (size_t)b * NT * CD;
  const unsigned short* h0 = Hb + (size_t)(n_base + l31) * CD + 8 * hh;
  const unsigned short* h1 = h0 + (size_t)32 * CD;
  float16v acc0, acc1;
#pragma unroll
  for (int r = 0; r < 16; r++) { acc0[r] = 0.f; acc1[r] = 0.f; }
#pragma unroll
  for (int s = 0; s < 16; s++) {
    bf16x8 af = *(const bf16x8*)(Arow + 16 * s);
    bf16x8 b0 = *(const bf16x8*)(h0 + 16 * s);
    bf16x8 b1 = *(const bf16x8*)(h1 + 16 * s);
    acc0 = __builtin_amdgcn_mfma_f32_32x32x16_bf16(af, b0, acc0, 0, 0, 0);
    acc1 = __builtin_amdgcn_mfma_f32_32x32x16_bf16(af, b1, acc1, 0, 0, 0);
  }
  float bj[16];
  int jr[16];
#pragma unroll
  for (int r = 0; r < 16; r++) {
    jr[r] = m_base + (r & 3) + 8 * (r >> 2) + 4 * hh;
    bj[r] = bias[jr[r]];
  }
#pragma unroll
  for (int half = 0; half < 2; half++) {
    int n = n_base + 32 * half + l31;
#pragma unroll
    for (int r = 0; r < 16; r++) {
      float val = (half ? acc1[r] : acc0[r]) + bj[r];
      int j = jr[r];
      if (j < 64) {
        qk[((size_t)b * NT + n) * 64 + j] = f2bf(val);
      } else {
        v[((size_t)b * CD + (j - 64)) * NT + n] = f2bf(val);
      }
    }
  }
}

// ---------------------------------------------------------------------------
// Fused attention v3: q-tile 128, e 256, key-split KHN. 8 waves/block.
// S phase: wave (qs=w&3, kj=w>>2) computes the S^T quadrant keys[32kj..+32)
// x q[32qs..+32) — all 8 waves busy, exp2 + pack into shared Pbuf.
// PV phase: wave (qih=w&1, epair=w>>1) computes a 2x2 tile block (qi in
// {2qih,2qih+1} x etile in {2epair,2epair+1}) -> per k-step 4 LDS reads feed
// 4 MFMAs (1.0 KB/MFMA vs 1.5 before — LDS-BW was the binding pipe).
// Unnormalized partials to P0..P3 + l partials to lp; proj combines.
// ---------------------------------------------------------------------------
template <int KHN>
__global__ __launch_bounds__(512, 4) void attn_fused(
    const unsigned short* __restrict__ qk, const unsigned short* __restrict__ V,
    unsigned short* __restrict__ P0, unsigned short* __restrict__ P1,
    unsigned short* __restrict__ P2, unsigned short* __restrict__ P3,
    float* __restrict__ lp) {
  constexpr int ITERS = (NT / KHN) / 64;
  int bx = blockIdx.x;
  int n0 = (bx / KHN) * 128;
  int kh = bx % KHN;
  int b = blockIdx.y;
  int tid = threadIdx.x, lane = tid & 63, w = tid >> 6;
  int l31 = lane & 31, hh = lane >> 5;
  int qs = w & 3, kj = w >> 2;      // S-phase quadrant
  int qih = w & 1, epair = w >> 1;  // PV-phase tile block

  __shared__ unsigned short Ks[64 * 36];    // 64 keys x 32 d (+pad)
  __shared__ unsigned short Vs[256 * 68];   // 256 e x 64 m (+pad)
  __shared__ unsigned short Pbuf[128 * 68]; // 128 q x 64 keys (+pad)

  const unsigned short* qkb = qk + (size_t)b * NT * 64;
  const unsigned short* Vb = V + (size_t)b * CD * NT;

  // Q fragments for this wave's S quadrant (B-operand: lane = q-row, k = d)
  bf16x8 qfr[2];
  {
    int n_g = n0 + 32 * qs + l31;
    qfr[0] = *(const bf16x8*)&qkb[(size_t)n_g * 64 + 8 * hh];
    qfr[1] = *(const bf16x8*)&qkb[(size_t)n_g * 64 + 8 * hh + 16];
  }

  int se = tid >> 1, smh = (tid & 1) * 32;  // V staging: e-row, m-half
  int skr = tid >> 2, skc = (tid & 3) * 8;  // K staging (tid<256)
  int mbase = kh * (NT / KHN);

  uint4v vreg[4];
  uint4v kreg;
  {
    const unsigned short* vp = &Vb[(size_t)se * NT + mbase + smh];
#pragma unroll
    for (int u = 0; u < 4; u++) vreg[u] = *(const uint4v*)(vp + 8 * u);
    if (tid < 256)
      kreg = *(const uint4v*)&qkb[(size_t)(mbase + skr) * 64 + 32 + skc];
  }

  float16v acc[2][2];
#pragma unroll
  for (int a = 0; a < 2; a++)
#pragma unroll
    for (int e2 = 0; e2 < 2; e2++)
#pragma unroll
      for (int r = 0; r < 16; r++) acc[a][e2][r] = 0.f;
  float lsum = 0.f;

  for (int it = 0; it < ITERS; it++) {
    // stage K(it); prefetch K(it+1)
    if (tid < 256) {
      *(uint4v*)&Ks[skr * 36 + skc] = kreg;
      if (it + 1 < ITERS) {
        int m1 = mbase + (it + 1) * 64;
        kreg = *(const uint4v*)&qkb[(size_t)(m1 + skr) * 64 + 32 + skc];
      }
    }
    __syncthreads();  // barrier1: Ks ready; Vs/Pbuf reads of it-1 done

    // stage V(it); prefetch V(it+1)
#pragma unroll
    for (int u = 0; u < 4; u++)
      *(uint4v*)&Vs[se * 68 + smh + 8 * u] = vreg[u];
    if (it + 1 < ITERS) {
      int m1 = mbase + (it + 1) * 64;
      const unsigned short* vp = &Vb[(size_t)se * NT + m1 + smh];
#pragma unroll
      for (int u = 0; u < 4; u++) vreg[u] = *(const uint4v*)(vp + 8 * u);
    }

    // S^T quadrant (all 8 waves): keys [32kj,+32) x q [32qs,+32)
    {
      float16v st;
#pragma unroll
      for (int r = 0; r < 16; r++) st[r] = 0.f;
#pragma unroll
      for (int s = 0; s < 2; s++) {
        bf16x8 af = *(const bf16x8*)&Ks[(32 * kj + l31) * 36 + 16 * s + 8 * hh];
        st = __builtin_amdgcn_mfma_f32_32x32x16_bf16(af, qfr[s], st, 0, 0, 0);
      }
      unsigned short* Prow = &Pbuf[(32 * qs + l31) * 68 + 32 * kj];
#pragma unroll
      for (int rq = 0; rq < 4; rq++) {
        float e0 = EXP2(st[4 * rq + 0]);
        float e1 = EXP2(st[4 * rq + 1]);
        float e2 = EXP2(st[4 * rq + 2]);
        float e3 = EXP2(st[4 * rq + 3]);
        lsum += (e0 + e1) + (e2 + e3);
        uint2v pw;
        pw[0] = __builtin_amdgcn_perm(__float_as_uint(e1), __float_as_uint(e0),
                                      0x07060302u);
        pw[1] = __builtin_amdgcn_perm(__float_as_uint(e3), __float_as_uint(e2),
                                      0x07060302u);
        *(uint2v*)&Prow[8 * rq + 4 * hh] = pw;
      }
    }
    __syncthreads();  // barrier2: Pbuf + Vs ready

    // PV: 4 k-steps; per step 2 P-frags + 2 V-frags -> 4 MFMAs
#pragma unroll
    for (int sp = 0; sp < 4; sp++) {
      bf16x8 a0 =
          *(const bf16x8*)&Pbuf[(32 * (2 * qih) + l31) * 68 + 16 * sp + 8 * hh];
      bf16x8 a1 = *(const bf16x8*)&Pbuf[(32 * (2 * qih + 1) + l31) * 68 +
                                        16 * sp + 8 * hh];
      bf16x8 b0 =
          *(const bf16x8*)&Vs[(32 * (2 * epair) + l31) * 68 + 16 * sp + 8 * hh];
      bf16x8 b1 = *(const bf16x8*)&Vs[(32 * (2 * epair + 1) + l31) * 68 +
                                      16 * sp + 8 * hh];
      acc[0][0] = __builtin_amdgcn_mfma_f32_32x32x16_bf16(a0, b0, acc[0][0], 0, 0, 0);
      acc[0][1] = __builtin_amdgcn_mfma_f32_32x32x16_bf16(a0, b1, acc[0][1], 0, 0, 0);
      acc[1][0] = __builtin_amdgcn_mfma_f32_32x32x16_bf16(a1, b0, acc[1][0], 0, 0, 0);
      acc[1][1] = __builtin_amdgcn_mfma_f32_32x32x16_bf16(a1, b1, acc[1][1], 0, 0, 0);
    }
  }

  // l partial for segment (kh,kj) over q rows [n0+32qs, +32)
  lsum += __shfl_xor(lsum, 32);
  if (hh == 0) {
    lp[(size_t)((kh * 2 + kj) * NB + b) * NT + n0 + 32 * qs + l31] = lsum;
  }
  // unnormalized partial O (C-layout: regs = q, lane = e)
  unsigned short* Pout =
      (kh == 0 ? P0 : kh == 1 ? P1 : kh == 2 ? P2 : P3) + (size_t)b * NT * CD;
#pragma unroll
  for (int a = 0; a < 2; a++) {
#pragma unroll
    for (int r = 0; r < 16; r++) {
      int nl = (r & 3) + 8 * (r >> 2) + 4 * hh;
      size_t row = (size_t)(n0 + 32 * (2 * qih + a) + nl) * CD;
#pragma unroll
      for (int e2 = 0; e2 < 2; e2++) {
        Pout[row + 32 * (2 * epair + e2) + l31] = f2bf(acc[a][e2][r]);
      }
    }
  }
}

// ---------------------------------------------------------------------------
// Proj GEMM + KHN-partial combine + bias + residual.
// ---------------------------------------------------------------------------
template <int KHN>
__device__ inline bf16x8 combineN(const unsigned short* const* ps, size_t off,
                                  float inv) {
  uint4v u[KHN];
#pragma unroll
  for (int k = 0; k < KHN; k++) u[k] = *(const uint4v*)(ps[k] + off);
  uint4v r;
#pragma unroll
  for (int j = 0; j < 4; j++) {
    float lo = 0.f, hi = 0.f;
#pragma unroll
    for (int k = 0; k < KHN; k++) {
      lo += __uint_as_float(u[k][j] << 16);
      hi += __uint_as_float(u[k][j] & 0xffff0000u);
    }
    lo *= inv;
    hi *= inv;
    r[j] = __builtin_amdgcn_perm(__float_as_uint(hi), __float_as_uint(lo),
                                 0x07060302u);
  }
  return *(bf16x8*)&r;
}

template <int KHN>
__global__ __launch_bounds__(256) void proj_gemm(
    const unsigned short* __restrict__ Wp, const unsigned short* __restrict__ P0,
    const unsigned short* __restrict__ P1,
    const unsigned short* __restrict__ P2,
    const unsigned short* __restrict__ P3, const float* __restrict__ lp,
    const float* __restrict__ bp, const float* __restrict__ x,
    float* __restrict__ out) {
  int nt = blockIdx.x, mt = blockIdx.y, b = blockIdx.z;
  int tid = threadIdx.x, lane = tid & 63;
  int w = tid >> 6, mi = w & 1, ni = w >> 1;
  int l31 = lane & 31, hh = lane >> 5;
  int m_base = mt * 64 + 32 * mi;
  int n_base = nt * 128 + 64 * ni;
  const unsigned short* Arow = Wp + (size_t)(m_base + l31) * 256 + 8 * hh;
  int nA = n_base + l31, nB = nA + 32;
  float lA = 0.f, lB = 0.f;
#pragma unroll
  for (int s4 = 0; s4 < 2 * KHN; s4++) {
    lA += lp[(size_t)(s4 * NB + b) * NT + nA];
    lB += lp[(size_t)(s4 * NB + b) * NT + nB];
  }
  float invA = 1.f / lA, invB = 1.f / lB;
  const unsigned short* psA[4];
  const unsigned short* psB[4];
  const unsigned short* bufs[4] = {P0, P1, P2, P3};
#pragma unroll
  for (int k = 0; k < KHN; k++) {
    psA[k] = bufs[k] + ((size_t)b * NT + nA) * CD + 8 * hh;
    psB[k] = bufs[k] + ((size_t)b * NT + nB) * CD + 8 * hh;
  }
  float16v acc0, acc1;
#pragma unroll
  for (int r = 0; r < 16; r++) { acc0[r] = 0.f; acc1[r] = 0.f; }
#pragma unroll
  for (int s = 0; s < 16; s++) {
    bf16x8 af = *(const bf16x8*)(Arow + 16 * s);
    bf16x8 b0 = combineN<KHN>(psA, (size_t)(16 * s), invA);
    bf16x8 b1 = combineN<KHN>(psB, (size_t)(16 * s), invB);
    acc0 = __builtin_amdgcn_mfma_f32_32x32x16_bf16(af, b0, acc0, 0, 0, 0);
    acc1 = __builtin_amdgcn_mfma_f32_32x32x16_bf16(af, b1, acc1, 0, 0, 0);
  }
#pragma unroll
  for (int half = 0; half < 2; half++) {
    int n = n_base + 32 * half + l31;
#pragma unroll
    for (int r = 0; r < 16; r++) {
      int f = m_base + (r & 3) + 8 * (r >> 2) + 4 * hh;
      size_t idx = ((size_t)b * CD + f) * NT + n;
      out[idx] = x[idx] + (half ? acc1[r] : acc0[r]) + bp[f];
    }
  }
}

extern "C" void kernel_launch(void* const* d_in, const int* in_sizes, int n_in,
                              void* d_out, int out_size, void* d_ws,
                              size_t ws_size, hipStream_t stream) {
  (void)in_sizes; (void)n_in; (void)out_size;
  const float* x = (const float*)d_in[0];
  const float* gamma = (const float*)d_in[1];
  const float* beta = (const float*)d_in[2];
  const float* wq = (const float*)d_in[3];
  const float* bq = (const float*)d_in[4];
  const float* wk = (const float*)d_in[5];
  const float* bk = (const float*)d_in[6];
  const float* wv = (const float*)d_in[7];
  const float* bv = (const float*)d_in[8];
  const float* wp = (const float*)d_in[9];
  const float* bp = (const float*)d_in[10];
  float* out = (float*)d_out;
  char* ws = (char*)d_ws;

  unsigned short* h_ws = (unsigned short*)ws;               // 8 MB (= P0)
  unsigned short* qk_ws = (unsigned short*)(ws + 8388608);  // 2 MB
  unsigned short* v_ws = (unsigned short*)(ws + 10485760);  // 8 MB
  unsigned short* P1 = (unsigned short*)(ws + 18874368);    // 8 MB
  unsigned short* P0 = h_ws;  // h dead after qkv; reused as partial 0

  // KHN=4 layout needs P2/P3 + smalls: end ~44.9 MB
  bool big = ws_size >= 44863488ull;
  unsigned short *P2, *P3, *wqkv_b, *wp_b;
  float *bias_q, *lp;
  if (big) {
    P2 = (unsigned short*)(ws + 27262976);      // 8 MB
    P3 = (unsigned short*)(ws + 35651584);      // 8 MB
    wqkv_b = (unsigned short*)(ws + 44040192);  // 160 KB
    wp_b = (unsigned short*)(ws + 44204032);    // 128 KB
    bias_q = (float*)(ws + 44335104);           // 1.25 KB
    lp = (float*)(ws + 44339200);               // 512 KB
  } else {
    P2 = P0;
    P3 = P1;
    wqkv_b = (unsigned short*)(ws + 27262976);  // 160 KB
    wp_b = (unsigned short*)(ws + 27426816);    // 128 KB
    bias_q = (float*)(ws + 27557888);           // 1.25 KB
    lp = (float*)(ws + 27559168);               // 256 KB
  }

  gn_pack<<<417, 512, 0, stream>>>(x, gamma, beta, wq, wk, wv, wp, bq, bk, bv,
                                   h_ws, wqkv_b, wp_b, bias_q);
  dim3 gq(32, 5, NB);
  qkv_gemm<<<gq, 256, 0, stream>>>(wqkv_b, h_ws, bias_q, qk_ws, v_ws);
  if (big) {
    dim3 ga(128, NB);
    attn_fused<4><<<ga, 512, 0, stream>>>(qk_ws, v_ws, P0, P1, P2, P3, lp);
    dim3 gp(32, 4, NB);
    proj_gemm<4><<<gp, 256, 0, stream>>>(wp_b, P0, P1, P2, P3, lp, bp, x, out);
  } else {
    dim3 ga(64, NB);
    attn_fused<2><<<ga, 512, 0, stream>>>(qk_ws, v_ws, P0, P1, P2, P3, lp);
    dim3 gp(32, 4, NB);
    proj_gemm<2><<<gp, 256, 0, stream>>>(wp_b, P0, P1, P2, P3, lp, bp, x, out);
  }
}

// Round 10
// 194.999 us; speedup vs baseline: 1.0532x; 1.0532x over previous
//
#include <hip/hip_runtime.h>
#include <hip/hip_bf16.h>

// Problem constants (B=4, C=256, H=W=64, N=4096, G=32, DQK=32)
#define NB 4
#define CD 256
#define NT 4096
#define DQ 32

typedef __attribute__((ext_vector_type(8))) __bf16 bf16x8;
typedef __attribute__((ext_vector_type(16))) float float16v;
typedef __attribute__((ext_vector_type(4))) unsigned int uint4v;
typedef __attribute__((ext_vector_type(2))) unsigned int uint2v;

#if __has_builtin(__builtin_amdgcn_exp2f)
#define EXP2(x) __builtin_amdgcn_exp2f(x)
#else
#define EXP2(x) exp2f(x)
#endif

__device__ inline unsigned short f2bf(float f) {
  unsigned u = __float_as_uint(f);
  u += 0x7fffu + ((u >> 16) & 1u);
  return (unsigned short)(u >> 16);
}

// ---------------------------------------------------------------------------
// gn_pack: blocks 0..127 do full GroupNorm for one (b,g) (block-local stats
// + apply — no grid dependency), writing h[B][N][C] bf16. Blocks 128..416
// pack weights to bf16 (scale2 = log2(e)/sqrt(32) folded into wq/bq so
// attention uses exp2 directly). One dispatch replaces three. [proven R8]
// ---------------------------------------------------------------------------
__global__ __launch_bounds__(512) void gn_pack(
    const float* __restrict__ x, const float* __restrict__ gamma,
    const float* __restrict__ beta, const float* __restrict__ wq,
    const float* __restrict__ wk, const float* __restrict__ wv,
    const float* __restrict__ wp, const float* __restrict__ bq,
    const float* __restrict__ bk, const float* __restrict__ bv,
    unsigned short* __restrict__ h, unsigned short* __restrict__ wqkv,
    unsigned short* __restrict__ wpb, float* __restrict__ bias) {
  int bx = blockIdx.x;
  int tid = threadIdx.x;
  if (bx < 128) {
    int bg = bx;  // b*32+g
    const float4* xp = (const float4*)(x + (size_t)bg * 32768);
    float s = 0.f, ss = 0.f;
#pragma unroll
    for (int i = 0; i < 16; i++) {
      float4 v = xp[tid + 512 * i];
      s += v.x + v.y + v.z + v.w;
      ss += v.x * v.x + v.y * v.y + v.z * v.z + v.w * v.w;
    }
    int wid = tid >> 6, lane = tid & 63;
#pragma unroll
    for (int off = 32; off >= 1; off >>= 1) {
      s += __shfl_xor(s, off);
      ss += __shfl_xor(ss, off);
    }
    __shared__ float red[16];
    __shared__ float stat[2];
    if (lane == 0) { red[wid] = s; red[8 + wid] = ss; }
    __syncthreads();
    if (tid == 0) {
      float S = 0.f, SS = 0.f;
#pragma unroll
      for (int j = 0; j < 8; j++) { S += red[j]; SS += red[8 + j]; }
      float mu = S * (1.f / 32768.f);
      float var = SS * (1.f / 32768.f) - mu * mu;
      stat[0] = mu;
      stat[1] = rsqrtf(var + 1e-5f);
    }
    __syncthreads();
    float mu = stat[0], rstd = stat[1];
    int b = bg >> 5, g = bg & 31, c0 = g * 8;
    float gam[8], bet[8];
#pragma unroll
    for (int j = 0; j < 8; j++) {
      gam[j] = gamma[c0 + j];
      bet[j] = beta[c0 + j];
    }
    const float* xb = x + (size_t)bg * 32768;
#pragma unroll
    for (int i = 0; i < 8; i++) {
      int n = 512 * i + tid;
      unsigned short hv[8];
#pragma unroll
      for (int j = 0; j < 8; j++) {
        float y = (xb[j * NT + n] - mu) * rstd * gam[j] + bet[j];
        hv[j] = f2bf(y);
      }
      *(uint4v*)(h + ((size_t)(b * NT + n) * CD + c0)) = *(uint4v*)hv;
    }
  } else {
    const float scale2 = 0.2550348909867343f;  // log2(e)/sqrt(32)
    int i = (bx - 128) * 512 + tid;
    if (i < 320 * 256) {
      int j = i >> 8, c = i & 255;
      float v;
      if (j < 32) v = wq[j * 256 + c] * scale2;
      else if (j < 64) v = wk[(j - 32) * 256 + c];
      else v = wv[(j - 64) * 256 + c];
      wqkv[i] = f2bf(v);
    } else if (i < 320 * 256 + 256 * 256) {
      int k = i - 320 * 256;
      wpb[k] = f2bf(wp[k]);
    } else if (i < 320 * 256 + 256 * 256 + 320) {
      int j = i - (320 * 256 + 256 * 256);
      float v;
      if (j < 32) v = bq[j] * scale2;
      else if (j < 64) v = bk[j - 32];
      else v = bv[j - 64];
      bias[j] = v;
    }
  }
}

// ---------------------------------------------------------------------------
// QKV GEMM — zero LDS, zero barriers (proven R5 form).
// ---------------------------------------------------------------------------
__global__ __launch_bounds__(256) void qkv_gemm(
    const unsigned short* __restrict__ A, const unsigned short* __restrict__ H,
    const float* __restrict__ bias, unsigned short* __restrict__ qk,
    unsigned short* __restrict__ v) {
  int nt = blockIdx.x, mt = blockIdx.y, b = blockIdx.z;
  int tid = threadIdx.x, lane = tid & 63;
  int w = tid >> 6, mi = w & 1, ni = w >> 1;
  int l31 = lane & 31, hh = lane >> 5;
  int m_base = mt * 64 + 32 * mi;
  int n_base = nt * 128 + 64 * ni;
  const unsigned short* Arow = A + (size_t)(m_base + l31) * 256 + 8 * hh;
  const unsigned short* Hb = H + (size_t)b * NT * CD;
  const unsigned short* h0 = Hb + (size_t)(n_base + l31) * CD + 8 * hh;
  const unsigned short* h1 = h0 + (size_t)32 * CD;
  float16v acc0, acc1;
#pragma unroll
  for (int r = 0; r < 16; r++) { acc0[r] = 0.f; acc1[r] = 0.f; }
#pragma unroll
  for (int s = 0; s < 16; s++) {
    bf16x8 af = *(const bf16x8*)(Arow + 16 * s);
    bf16x8 b0 = *(const bf16x8*)(h0 + 16 * s);
    bf16x8 b1 = *(const bf16x8*)(h1 + 16 * s);
    acc0 = __builtin_amdgcn_mfma_f32_32x32x16_bf16(af, b0, acc0, 0, 0, 0);
    acc1 = __builtin_amdgcn_mfma_f32_32x32x16_bf16(af, b1, acc1, 0, 0, 0);
  }
  float bj[16];
  int jr[16];
#pragma unroll
  for (int r = 0; r < 16; r++) {
    jr[r] = m_base + (r & 3) + 8 * (r >> 2) + 4 * hh;
    bj[r] = bias[jr[r]];
  }
#pragma unroll
  for (int half = 0; half < 2; half++) {
    int n = n_base + 32 * half + l31;
#pragma unroll
    for (int r = 0; r < 16; r++) {
      float val = (half ? acc1[r] : acc0[r]) + bj[r];
      int j = jr[r];
      if (j < 64) {
        qk[((size_t)b * NT + n) * 64 + j] = f2bf(val);
      } else {
        v[((size_t)b * CD + (j - 64)) * NT + n] = f2bf(val);
      }
    }
  }
}

// ---------------------------------------------------------------------------
// Fused attention, 512-thread blocks sharing S across the full e=256 range
// (proven R7 form — best passing attn at 61.9us). 8 waves = 2(qi) x 2(kj) x
// 2(eo). Waves eo=0 compute the S^T quadrant keys[32kj..+32) x q[32qi..+32),
// exp2 + pack into shared Pbuf; all 8 waves do PV on 2 e-tiles each.
// Key-split x2 (kh): unnormalized partials to Pa/Pb + l to lp; proj combines
// (no cross-block sync — R9's fence+flag combine failed correctness).
// ---------------------------------------------------------------------------
__global__ __launch_bounds__(512, 4) void attn_fused(
    const unsigned short* __restrict__ qk, const unsigned short* __restrict__ V,
    unsigned short* __restrict__ Pa, unsigned short* __restrict__ Pb,
    float* __restrict__ lp4) {
  int bx = blockIdx.x;
  int n0 = (bx >> 1) * 64;  // q-tile base
  int kh = bx & 1;          // key half
  int b = blockIdx.y;
  int tid = threadIdx.x, lane = tid & 63, w = tid >> 6;
  int qi = w & 1, kj = (w >> 1) & 1, eo = w >> 2;
  int l31 = lane & 31, hh = lane >> 5;

  __shared__ unsigned short Ks[64 * 36];        // 64 keys x 32 d (+4 pad)
  __shared__ unsigned short Vs[256 * 68];       // 256 e x 64 m (+4 pad)
  __shared__ unsigned short Pbuf[2 * 32 * 68];  // [qi][32 q][64 keys (+4 pad)]

  const unsigned short* qkb = qk + (size_t)b * NT * 64;
  const unsigned short* Vb = V + (size_t)b * CD * NT;

  // Q fragments (B-operand: lane&31 = q-row, k = d)
  int n_g = n0 + 32 * qi + l31;
  bf16x8 qfr[2];
  qfr[0] = *(const bf16x8*)&qkb[(size_t)n_g * 64 + 8 * hh];
  qfr[1] = *(const bf16x8*)&qkb[(size_t)n_g * 64 + 8 * hh + 16];

  // staging assignments
  int se = tid >> 1, smh = (tid & 1) * 32;  // V: e-row (0..255), 32-wide m-half
  int skr = tid >> 2, skc = (tid & 3) * 8;  // K (tid<256): row, 8-wide d

  int mbase = kh * 2048;
  uint4v vreg[4];
  uint4v kreg;
  {
    const unsigned short* vp = &Vb[(size_t)se * NT + mbase + smh];
#pragma unroll
    for (int u = 0; u < 4; u++) vreg[u] = *(const uint4v*)(vp + 8 * u);
    if (tid < 256)
      kreg = *(const uint4v*)&qkb[(size_t)(mbase + skr) * 64 + 32 + skc];
  }

  float16v acc[2];
#pragma unroll
  for (int et = 0; et < 2; et++)
#pragma unroll
    for (int r = 0; r < 16; r++) acc[et][r] = 0.f;
  float lsum = 0.f;
  unsigned short* Prow = &Pbuf[(qi * 32 + l31) * 68];

  for (int it = 0; it < 32; it++) {
    // stage K(it); prefetch K(it+1)
    if (tid < 256) {
      *(uint4v*)&Ks[skr * 36 + skc] = kreg;
      if (it + 1 < 32) {
        int m1 = mbase + (it + 1) * 64;
        kreg = *(const uint4v*)&qkb[(size_t)(m1 + skr) * 64 + 32 + skc];
      }
    }
    __syncthreads();  // barrier1: Ks ready; Vs/Pbuf reads of it-1 done

    // stage V(it) (read after barrier2); prefetch V(it+1)
#pragma unroll
    for (int u = 0; u < 4; u++)
      *(uint4v*)&Vs[se * 68 + smh + 8 * u] = vreg[u];
    if (it + 1 < 32) {
      int m1 = mbase + (it + 1) * 64;
      const unsigned short* vp = &Vb[(size_t)se * NT + m1 + smh];
#pragma unroll
      for (int u = 0; u < 4; u++) vreg[u] = *(const uint4v*)(vp + 8 * u);
    }

    if (eo == 0) {
      // S^T quadrant: keys [32kj,+32) x q-rows [32qi,+32)
      float16v st;
#pragma unroll
      for (int r = 0; r < 16; r++) st[r] = 0.f;
#pragma unroll
      for (int s = 0; s < 2; s++) {
        bf16x8 af = *(const bf16x8*)&Ks[(32 * kj + l31) * 36 + 16 * s + 8 * hh];
        st = __builtin_amdgcn_mfma_f32_32x32x16_bf16(af, qfr[s], st, 0, 0, 0);
      }
      // exp2 + pack pairs + write shared P rows (key cols 32kj..32kj+31)
#pragma unroll
      for (int rq = 0; rq < 4; rq++) {
        float e0 = EXP2(st[4 * rq + 0]);
        float e1 = EXP2(st[4 * rq + 1]);
        float e2 = EXP2(st[4 * rq + 2]);
        float e3 = EXP2(st[4 * rq + 3]);
        lsum += (e0 + e1) + (e2 + e3);
        uint2v pw;
        pw[0] = __builtin_amdgcn_perm(__float_as_uint(e1), __float_as_uint(e0),
                                      0x07060302u);
        pw[1] = __builtin_amdgcn_perm(__float_as_uint(e3), __float_as_uint(e2),
                                      0x07060302u);
        *(uint2v*)&Prow[8 * rq + 4 * hh + 32 * kj] = pw;
      }
    }
    __syncthreads();  // barrier2: Pbuf + Vs ready

    // PV: all 8 waves, 2 e-tiles each (e-tile = 4*eo + 2*kj + et)
#pragma unroll
    for (int sp = 0; sp < 4; sp++) {
      bf16x8 afr =
          *(const bf16x8*)&Pbuf[(qi * 32 + l31) * 68 + 16 * sp + 8 * hh];
#pragma unroll
      for (int et = 0; et < 2; et++) {
        int etile = 4 * eo + 2 * kj + et;
        bf16x8 bfr =
            *(const bf16x8*)&Vs[(32 * etile + l31) * 68 + 16 * sp + 8 * hh];
        acc[et] =
            __builtin_amdgcn_mfma_f32_32x32x16_bf16(afr, bfr, acc[et], 0, 0, 0);
      }
    }
  }

  // l partials: wave (qi,kj,eo=0) holds keys 32kj range; combine hh halves
  if (eo == 0) {
    lsum += __shfl_xor(lsum, 32);
    if (hh == 0) {
      lp4[(size_t)((kh * 2 + kj) * NB + b) * NT + n0 + 32 * qi + l31] = lsum;
    }
  }
  // unnormalized partial O
  unsigned short* Pout = (kh ? Pb : Pa) + (size_t)b * NT * CD;
#pragma unroll
  for (int r = 0; r < 16; r++) {
    int nl = (r & 3) + 8 * (r >> 2) + 4 * hh;
    size_t row = (size_t)(n0 + 32 * qi + nl) * CD + l31;
#pragma unroll
    for (int et = 0; et < 2; et++) {
      int etile = 4 * eo + 2 * kj + et;
      Pout[row + 32 * etile] = f2bf(acc[et][r]);
    }
  }
}

// ---------------------------------------------------------------------------
// Proj GEMM + partial-combine + bias + residual (proven R7 form).
// ---------------------------------------------------------------------------
__device__ inline bf16x8 combine_frag(const unsigned short* p0,
                                      const unsigned short* p1, float inv) {
  uint4v ua = *(const uint4v*)p0;
  uint4v ub = *(const uint4v*)p1;
  uint4v r;
#pragma unroll
  for (int j = 0; j < 4; j++) {
    float lo = __uint_as_float(ua[j] << 16) + __uint_as_float(ub[j] << 16);
    float hi = __uint_as_float(ua[j] & 0xffff0000u) +
               __uint_as_float(ub[j] & 0xffff0000u);
    lo *= inv;
    hi *= inv;
    r[j] = __builtin_amdgcn_perm(__float_as_uint(hi), __float_as_uint(lo),
                                 0x07060302u);
  }
  return *(bf16x8*)&r;
}

__global__ __launch_bounds__(256) void proj_gemm(
    const unsigned short* __restrict__ Wp, const unsigned short* __restrict__ Pa,
    const unsigned short* __restrict__ Pb, const float* __restrict__ lp4,
    const float* __restrict__ bp, const float* __restrict__ x,
    float* __restrict__ out) {
  int nt = blockIdx.x, mt = blockIdx.y, b = blockIdx.z;
  int tid = threadIdx.x, lane = tid & 63;
  int w = tid >> 6, mi = w & 1, ni = w >> 1;
  int l31 = lane & 31, hh = lane >> 5;
  int m_base = mt * 64 + 32 * mi;
  int n_base = nt * 128 + 64 * ni;
  const unsigned short* Arow = Wp + (size_t)(m_base + l31) * 256 + 8 * hh;
  int nA = n_base + l31, nB = nA + 32;
  float lA = 0.f, lB = 0.f;
#pragma unroll
  for (int s4 = 0; s4 < 4; s4++) {
    lA += lp4[(size_t)(s4 * NB + b) * NT + nA];
    lB += lp4[(size_t)(s4 * NB + b) * NT + nB];
  }
  float invA = 1.f / lA, invB = 1.f / lB;
  const unsigned short* a0 = Pa + ((size_t)b * NT + nA) * CD + 8 * hh;
  const unsigned short* a1 = Pa + ((size_t)b * NT + nB) * CD + 8 * hh;
  const unsigned short* c0 = Pb + ((size_t)b * NT + nA) * CD + 8 * hh;
  const unsigned short* c1 = Pb + ((size_t)b * NT + nB) * CD + 8 * hh;
  float16v acc0, acc1;
#pragma unroll
  for (int r = 0; r < 16; r++) { acc0[r] = 0.f; acc1[r] = 0.f; }
#pragma unroll
  for (int s = 0; s < 16; s++) {
    bf16x8 af = *(const bf16x8*)(Arow + 16 * s);
    bf16x8 b0 = combine_frag(a0 + 16 * s, c0 + 16 * s, invA);
    bf16x8 b1 = combine_frag(a1 + 16 * s, c1 + 16 * s, invB);
    acc0 = __builtin_amdgcn_mfma_f32_32x32x16_bf16(af, b0, acc0, 0, 0, 0);
    acc1 = __builtin_amdgcn_mfma_f32_32x32x16_bf16(af, b1, acc1, 0, 0, 0);
  }
#pragma unroll
  for (int half = 0; half < 2; half++) {
    int n = n_base + 32 * half + l31;
#pragma unroll
    for (int r = 0; r < 16; r++) {
      int f = m_base + (r & 3) + 8 * (r >> 2) + 4 * hh;
      size_t idx = ((size_t)b * CD + f) * NT + n;
      out[idx] = x[idx] + (half ? acc1[r] : acc0[r]) + bp[f];
    }
  }
}

extern "C" void kernel_launch(void* const* d_in, const int* in_sizes, int n_in,
                              void* d_out, int out_size, void* d_ws,
                              size_t ws_size, hipStream_t stream) {
  (void)in_sizes; (void)n_in; (void)out_size; (void)ws_size;
  const float* x = (const float*)d_in[0];
  const float* gamma = (const float*)d_in[1];
  const float* beta = (const float*)d_in[2];
  const float* wq = (const float*)d_in[3];
  const float* bq = (const float*)d_in[4];
  const float* wk = (const float*)d_in[5];
  const float* bk = (const float*)d_in[6];
  const float* wv = (const float*)d_in[7];
  const float* bv = (const float*)d_in[8];
  const float* wp = (const float*)d_in[9];
  const float* bp = (const float*)d_in[10];
  float* out = (float*)d_out;

  char* ws = (char*)d_ws;
  unsigned short* h_ws = (unsigned short*)ws;               // 8 MB (= Pa)
  unsigned short* qk_ws = (unsigned short*)(ws + 8388608);  // 2 MB
  unsigned short* v_ws = (unsigned short*)(ws + 10485760);  // 8 MB
  unsigned short* o_ws = (unsigned short*)(ws + 18874368);  // 8 MB (= Pb)
  unsigned short* wqkv_b = (unsigned short*)(ws + 27262976);  // 160 KB
  unsigned short* wp_b = (unsigned short*)(ws + 27426816);    // 128 KB
  float* bias_q = (float*)(ws + 27557888);                    // 1.25 KB
  float* lp = (float*)(ws + 27559168);                        // 256 KB

  gn_pack<<<417, 512, 0, stream>>>(x, gamma, beta, wq, wk, wv, wp, bq, bk, bv,
                                   h_ws, wqkv_b, wp_b, bias_q);
  dim3 gq(32, 5, NB);
  qkv_gemm<<<gq, 256, 0, stream>>>(wqkv_b, h_ws, bias_q, qk_ws, v_ws);
  dim3 ga(128, NB);
  attn_fused<<<ga, 512, 0, stream>>>(qk_ws, v_ws, h_ws, o_ws, lp);
  dim3 gp(32, 4, NB);
  proj_gemm<<<gp, 256, 0, stream>>>(wp_b, h_ws, o_ws, lp, bp, x, out);
}